// Round 1
// baseline (357.420 us; speedup 1.0000x reference)
//
#include <hip/hip_runtime.h>

// Problem dims (fixed by setup_inputs): x[2,8,540,960] f32, filt[16,8] f32,
// scale_factor=3 (runtime int input), out[2,8,1620,2880] f32.
#define BC 16
#define H 540
#define W 960
#define OH 1620
#define OW 2880
#define NOUT (16u * 1620u * 2880u)   // 74,649,600 < 2^31, divisible by 4

__global__ __launch_bounds__(256) void vtm_upsample(
    const float* __restrict__ x,
    const float* __restrict__ filt,
    const int* __restrict__ scale_p,
    float* __restrict__ out)
{
    __shared__ float s_f[16][8];
    __shared__ float s_sum[16];
    const int tid = threadIdx.x;
    if (tid < 128) ((float*)s_f)[tid] = filt[tid];
    __syncthreads();
    if (tid < 16) {
        float s = 0.f;
        #pragma unroll
        for (int k = 0; k < 8; ++k) s += s_f[tid][k];
        s_sum[tid] = s;
    }
    __syncthreads();

    const unsigned scale = (unsigned)scale_p[0];
    const float inv = 1.0f / 4096.0f;      // exact power of two, same as /2**12
    const unsigned nvec = NOUT / 4u;
    const unsigned stride = gridDim.x * blockDim.x;

    for (unsigned v = blockIdx.x * blockDim.x + (unsigned)tid; v < nvec; v += stride) {
        const unsigned p = v * 4u;
        const unsigned ox0 = p % OW;       // magic-mul, compile-time divisor
        const unsigned rr  = p / OW;
        const unsigned oy  = rr % OH;
        const unsigned bc  = rr / OH;
        const float* __restrict__ xp = x + (size_t)bc * (H * W);

        // Row phase table (replicates: ref=int(oy*16384/scale); int=ref>>4; frac=ref&15)
        const unsigned refy = (oy * 16384u) / scale;
        const int iy = (int)(refy >> 4);
        const int fy = (int)(refy & 15u);
        const int r0 = min(max(iy - 3, 0), H - 1);
        const int r7 = min(max(iy + 4, 0), H - 1);
        const bool rowSat = (r0 == r7);    // all 8 vertical taps clamp to same row
        const float Sh = s_sum[fy];

        float vals[4];
        #pragma unroll
        for (int u = 0; u < 4; ++u) {
            const unsigned ox = ox0 + (unsigned)u;
            const unsigned refx = (ox * 16384u) / scale;
            const int ix = (int)(refx >> 4);
            const int fx = (int)(refx & 15u);
            const int c0 = min(max(ix - 3, 0), W - 1);
            const int c7 = min(max(ix + 4, 0), W - 1);
            const bool colSat = (c0 == c7);  // all 8 horizontal taps clamp to same col
            const float Sw = s_sum[fx];

            float val;
            if (colSat && rowSat) {
                // both dims collapsed: single load (L1 broadcast for most of image)
                val = xp[r0 * W + c0] * Sw * Sh;
            } else if (colSat) {
                float acc = 0.f;
                #pragma unroll
                for (int j = 0; j < 8; ++j) {
                    const int ry = min(max(iy + j - 3, 0), H - 1);
                    acc = fmaf(s_f[fy][j], xp[ry * W + c0], acc);
                }
                val = acc * Sw;
            } else if (rowSat) {
                float acc = 0.f;
                #pragma unroll
                for (int k = 0; k < 8; ++k) {
                    const int cx = min(max(ix + k - 3, 0), W - 1);
                    acc = fmaf(s_f[fx][k], xp[r0 * W + cx], acc);
                }
                val = acc * Sh;
            } else {
                // full 8x8 general path (only ~96 outputs for scale=3)
                float acc = 0.f;
                #pragma unroll
                for (int j = 0; j < 8; ++j) {
                    const int ry = min(max(iy + j - 3, 0), H - 1);
                    const float* __restrict__ rp = xp + ry * W;
                    float h = 0.f;
                    #pragma unroll
                    for (int k = 0; k < 8; ++k) {
                        const int cx = min(max(ix + k - 3, 0), W - 1);
                        h = fmaf(s_f[fx][k], rp[cx], h);
                    }
                    acc = fmaf(s_f[fy][j], h, acc);
                }
                val = acc;
            }
            vals[u] = val * inv;
        }
        float4 res = make_float4(vals[0], vals[1], vals[2], vals[3]);
        *reinterpret_cast<float4*>(out + p) = res;   // coalesced 16B store
    }
}

extern "C" void kernel_launch(void* const* d_in, const int* in_sizes, int n_in,
                              void* d_out, int out_size, void* d_ws, size_t ws_size,
                              hipStream_t stream) {
    const float* x      = (const float*)d_in[0];
    const float* filt   = (const float*)d_in[1];
    const int*   scale_p= (const int*)d_in[2];
    float* out = (float*)d_out;
    dim3 grid(4096), block(256);
    vtm_upsample<<<grid, block, 0, stream>>>(x, filt, scale_p, out);
}